// Round 14
// baseline (9989.198 us; speedup 1.0000x reference)
//
#include <hip/hip_runtime.h>
#include <math.h>

#define VOCAB 32000
#define HID   1024
#define BATCH 8
#define SEQ   512
#define GD    (4*HID)       // 4096 gate width
#define ROWS  (BATCH*SEQ)   // 4096

typedef __attribute__((ext_vector_type(8))) short short8;
typedef __attribute__((ext_vector_type(4))) float f32x4;

__device__ __forceinline__ float hi_f32(float x) {
    return __uint_as_float(__float_as_uint(x) & 0xFFFF0000u);
}
// packed word: hi bf16 bits in high half, lo bf16 bits in low half
__device__ __forceinline__ unsigned pack_pair(float x) {
    unsigned hb = __float_as_uint(x) & 0xFFFF0000u;
    float lo = x - __uint_as_float(hb);
    return hb | (__float_as_uint(lo) >> 16);
}
__device__ __forceinline__ unsigned pack_hi2(float x, float y) {
    return (__float_as_uint(x) >> 16) | (__float_as_uint(y) & 0xFFFF0000u);
}

// async 16B/lane global->LDS (dest = wave-uniform base + lane*16)
__device__ __forceinline__ void gload16(const void* g, void* l) {
    __builtin_amdgcn_global_load_lds(
        (__attribute__((address_space(1))) void*)g,
        (__attribute__((address_space(3))) void*)l, 16, 0, 0);
}

// ---------------------------------------------------------------------------
// 1) Embedding gather, split: emb_hi/lo[row][h] = split(w_out[h][ids[row]])
// ---------------------------------------------------------------------------
__global__ __launch_bounds__(256) void k_gather_split(const int* __restrict__ ids,
                                                      const float* __restrict__ w_out,
                                                      unsigned short* __restrict__ emb_hi,
                                                      unsigned short* __restrict__ emb_lo)
{
    int row = blockIdx.x;            // 0..4095
    int id  = ids[row];
    const float* src = w_out + id;   // column id, stride VOCAB
    for (int h = threadIdx.x; h < HID; h += 256) {
        float v  = src[(size_t)h * VOCAB];
        float lo = v - hi_f32(v);
        emb_hi[(size_t)row*HID + h] = (unsigned short)(__float_as_uint(v)  >> 16);
        emb_lo[(size_t)row*HID + h] = (unsigned short)(__float_as_uint(lo) >> 16);
    }
}

// ---------------------------------------------------------------------------
// 2) Transpose + split: W[K=1024][N] f32 -> hiT/loT[N][1024] bf16 bits
// ---------------------------------------------------------------------------
__global__ __launch_bounds__(256) void k_transsplit(const float* __restrict__ W,
                                                    unsigned short* __restrict__ hiT,
                                                    unsigned short* __restrict__ loT,
                                                    int N)
{
    __shared__ float tile[32][33];
    int tx = threadIdx.x, ty = threadIdx.y;
    int x = blockIdx.x*32 + tx;      // N
    int y = blockIdx.y*32 + ty;      // K
    #pragma unroll
    for (int i = 0; i < 32; i += 8)
        tile[ty + i][tx] = W[(size_t)(y + i)*N + x];
    __syncthreads();
    int n = blockIdx.x*32 + ty;
    int k = blockIdx.y*32 + tx;
    #pragma unroll
    for (int i = 0; i < 32; i += 8) {
        float v  = tile[tx][ty + i];
        float lo = v - hi_f32(v);
        hiT[(size_t)(n + i)*HID + k] = (unsigned short)(__float_as_uint(v)  >> 16);
        loT[(size_t)(n + i)*HID + k] = (unsigned short)(__float_as_uint(lo) >> 16);
    }
}

// ---------------------------------------------------------------------------
// 3) Fast split-bf16 MFMA GEMM, all operands K-major bf16 bits (R8 proven).
// ---------------------------------------------------------------------------
#define GBM 128
#define GBN 128
#define GBK 32

__global__ __launch_bounds__(256) void k_gemm_fast(
    const unsigned short* __restrict__ Ah,  const unsigned short* __restrict__ Al,
    const unsigned short* __restrict__ BhT, const unsigned short* __restrict__ BlT,
    const float* __restrict__ bias, float* __restrict__ C,
    int M, int N, int K)
{
    __shared__ __align__(16) unsigned short lds[4][4096];  // Ah,Al,Bh,Bl: 8KB each

    const int tid  = threadIdx.x;
    const int lane = tid & 63;
    const int wid  = tid >> 6;
    const int wm = wid >> 1, wn = wid & 1;
    const int l15 = lane & 15, l4 = lane >> 4;
    const int brow = blockIdx.y * GBM;
    const int bcol = blockIdx.x * GBN;

    const int lhi  = lane >> 3;              // 0..7
    const int c8   = (lane & 7) ^ lhi;       // (g&7) == lhi for both chunks
    const int koff = (c8 & 3) * 8;           // element offset in k
    const int r0   = 32*wid + 2*lhi + (c8 >> 2);
    const int r1   = r0 + 16;
    const size_t a0 = (size_t)(brow + r0)*K + koff;
    const size_t a1 = (size_t)(brow + r1)*K + koff;
    const size_t b0 = (size_t)(bcol + r0)*K + koff;
    const size_t b1 = (size_t)(bcol + r1)*K + koff;
    char* lbase = (char*)&lds[0][0];
    const int cb0 = wid*2048, cb1 = wid*2048 + 1024;  // wave-uniform chunk bases

    const int ra = wm*64 + l15;
    const int ga = ra >> 1;
    const int abyte = ga*128 + (((((ra & 1) << 2) | l4) ^ (ga & 7)) << 4);
    const int rb = wn*64 + l15;
    const int gb = rb >> 1;
    const int bbyte = gb*128 + (((((rb & 1) << 2) | l4) ^ (gb & 7)) << 4);

    f32x4 acc[4][4] = {};

    for (int k0 = 0; k0 < K; k0 += GBK) {
        gload16(Ah  + a0 + k0, lbase         + cb0);
        gload16(Ah  + a1 + k0, lbase         + cb1);
        gload16(Al  + a0 + k0, lbase + 8192  + cb0);
        gload16(Al  + a1 + k0, lbase + 8192  + cb1);
        gload16(BhT + b0 + k0, lbase + 16384 + cb0);
        gload16(BhT + b1 + k0, lbase + 16384 + cb1);
        gload16(BlT + b0 + k0, lbase + 24576 + cb0);
        gload16(BlT + b1 + k0, lbase + 24576 + cb1);
        __syncthreads();

        short8 ah[4], al[4], bh[4], bl[4];
        #pragma unroll
        for (int m = 0; m < 4; ++m) {
            ah[m] = *(const short8*)(lbase         + abyte + m*1024);
            al[m] = *(const short8*)(lbase + 8192  + abyte + m*1024);
        }
        #pragma unroll
        for (int n = 0; n < 4; ++n) {
            bh[n] = *(const short8*)(lbase + 16384 + bbyte + n*1024);
            bl[n] = *(const short8*)(lbase + 24576 + bbyte + n*1024);
        }
        #pragma unroll
        for (int n = 0; n < 4; ++n)
            #pragma unroll
            for (int m = 0; m < 4; ++m) {
                acc[m][n] = __builtin_amdgcn_mfma_f32_16x16x32_bf16(ah[m], bh[n], acc[m][n], 0, 0, 0);
                acc[m][n] = __builtin_amdgcn_mfma_f32_16x16x32_bf16(ah[m], bl[n], acc[m][n], 0, 0, 0);
                acc[m][n] = __builtin_amdgcn_mfma_f32_16x16x32_bf16(al[m], bh[n], acc[m][n], 0, 0, 0);
            }
        __syncthreads();
    }

    #pragma unroll
    for (int n = 0; n < 4; ++n) {
        int col = bcol + wn*64 + n*16 + l15;
        float bv = bias[col];
        #pragma unroll
        for (int m = 0; m < 4; ++m) {
            int rbs = brow + wm*64 + m*16 + l4*4;
            #pragma unroll
            for (int r = 0; r < 4; ++r)
                C[(size_t)(rbs + r)*N + col] = acc[m][n][r] + bv;
        }
    }
}

// ---------------------------------------------------------------------------
// 3b) Fallback GEMM (in-kernel conversion, fp32 inputs) — Round-4 proven.
// ---------------------------------------------------------------------------
__global__ __launch_bounds__(256) void k_gemm_mfma(const float* __restrict__ A,
                                                   const float* __restrict__ B,
                                                   const float* __restrict__ bias,
                                                   float* __restrict__ C,
                                                   int M, int N, int K)
{
    __shared__ unsigned short As_hi[GBM][40];
    __shared__ unsigned short As_lo[GBM][40];
    __shared__ unsigned int   Bs[GBK][130];

    int tid  = threadIdx.x;
    int brow = blockIdx.y * GBM;
    int bcol = blockIdx.x * GBN;

    int lane = tid & 63;
    int wid  = tid >> 6;
    int wm   = wid >> 1;
    int wn   = wid & 1;
    int l15  = lane & 15;
    int l4   = lane >> 4;

    int a_m = tid >> 3;
    int a_c = tid & 7;
    int b_k = tid >> 5;
    int b_n = tid & 31;

    f32x4 acc[4][4] = {};

    for (int k0 = 0; k0 < K; k0 += GBK) {
        #pragma unroll
        for (int p = 0; p < 4; ++p) {
            int r = a_m + p*32;
            float4 v = *(const float4*)(A + (size_t)(brow + r)*K + k0 + a_c*4);
            unsigned h0 = pack_hi2(v.x, v.y);
            unsigned h1 = pack_hi2(v.z, v.w);
            float lx = v.x - hi_f32(v.x);
            float ly = v.y - hi_f32(v.y);
            float lz = v.z - hi_f32(v.z);
            float lw = v.w - hi_f32(v.w);
            unsigned l0 = pack_hi2(lx, ly);
            unsigned l1 = pack_hi2(lz, lw);
            *(uint2*)&As_hi[r][a_c*4] = make_uint2(h0, h1);
            *(uint2*)&As_lo[r][a_c*4] = make_uint2(l0, l1);
        }
        #pragma unroll
        for (int p = 0; p < 4; ++p) {
            int kk = b_k + p*8;
            float4 v = *(const float4*)(B + (size_t)(k0 + kk)*N + bcol + b_n*4);
            unsigned w0 = pack_pair(v.x);
            unsigned w1 = pack_pair(v.y);
            unsigned w2 = pack_pair(v.z);
            unsigned w3 = pack_pair(v.w);
            *(uint2*)&Bs[kk][b_n*4]     = make_uint2(w0, w1);
            *(uint2*)&Bs[kk][b_n*4 + 2] = make_uint2(w2, w3);
        }
        __syncthreads();

        short8 ah[4], al[4];
        #pragma unroll
        for (int m = 0; m < 4; ++m) {
            int r = wm*64 + m*16 + l15;
            ah[m] = *(const short8*)&As_hi[r][l4*8];
            al[m] = *(const short8*)&As_lo[r][l4*8];
        }

        #pragma unroll
        for (int n = 0; n < 4; ++n) {
            int col = wn*64 + n*16 + l15;
            unsigned w[8];
            #pragma unroll
            for (int j = 0; j < 8; ++j)
                w[j] = Bs[l4*8 + j][col];
            union { short8 v; unsigned d[4]; } bh, bl;
            #pragma unroll
            for (int d = 0; d < 4; ++d) {
                bh.d[d] = (w[2*d] >> 16)      | (w[2*d+1] & 0xFFFF0000u);
                bl.d[d] = (w[2*d] & 0xFFFFu)  | (w[2*d+1] << 16);
            }
            #pragma unroll
            for (int m = 0; m < 4; ++m) {
                acc[m][n] = __builtin_amdgcn_mfma_f32_16x16x32_bf16(ah[m], bh.v, acc[m][n], 0, 0, 0);
                acc[m][n] = __builtin_amdgcn_mfma_f32_16x16x32_bf16(ah[m], bl.v, acc[m][n], 0, 0, 0);
                acc[m][n] = __builtin_amdgcn_mfma_f32_16x16x32_bf16(al[m], bh.v, acc[m][n], 0, 0, 0);
            }
        }
        __syncthreads();
    }

    #pragma unroll
    for (int n = 0; n < 4; ++n) {
        int col = bcol + wn*64 + n*16 + l15;
        float bv = bias[col];
        #pragma unroll
        for (int m = 0; m < 4; ++m) {
            int rb = brow + wm*64 + m*16 + l4*4;
            #pragma unroll
            for (int r = 0; r < 4; ++r)
                C[(size_t)(rb + r)*N + col] = acc[m][n][r] + bv;
        }
    }
}

// ---------------------------------------------------------------------------
// 4) One LSTM timestep, v7: MFMA matvec, lean per-step launch.
//    64 blocks x 512 thr (8 waves, 2/SIMD). Block = 16 hidden cols x 4 gates.
//    Wave = (gate, K-half): 16 K-steps x 3 split-bf16 MFMA, 2 acc streams.
//    h(t-1) read as SEPARATE hi/lo bf16 ping-pong buffers (direct short8
//    loads, zero unpack); A-row = batch = l15&7 (rows 8-15 duplicate ->
//    C rows 8-15 garbage, never read). W^T hi/lo slice 128 KB/block
//    (L2-resident). Partial K-halves combined via 10 KB LDS; 128-thread
//    tail does activations and writes c, hs f32 (fallback A), hs hi/lo
//    (fast-path A, fused split), and the next ping-pong h.
//    Race-free across launches: reads pp_rd (written at t-1), writes pp_wr.
// ---------------------------------------------------------------------------
__global__ __launch_bounds__(512) void k_lstm_step3(
    const float* __restrict__ xg,
    const unsigned short* __restrict__ WhT_hi,   // [4096][1024] bf16 bits
    const unsigned short* __restrict__ WhT_lo,
    const unsigned short* __restrict__ pp_rd_hi, // [8][1024] h(t-1)
    const unsigned short* __restrict__ pp_rd_lo,
    unsigned short* __restrict__ pp_wr_hi,       // [8][1024] h(t)
    unsigned short* __restrict__ pp_wr_lo,
    float* __restrict__ c_state,
    float* __restrict__ hs_f32,                  // [4096][1024] (fallback A)
    unsigned short* __restrict__ hs_hi,          // [4096][1024] (fast A)
    unsigned short* __restrict__ hs_lo,
    int t)
{
    __shared__ float g_sm[2][4][16][20];   // [khalf][gate][col][batch(+pad)]

    const int tid  = threadIdx.x;
    const int lane = tid & 63;
    const int wv   = tid >> 6;        // 0..7
    const int gate = wv & 3;
    const int kh   = wv >> 2;         // K-half 0..1
    const int l15  = lane & 15;
    const int l4   = lane >> 4;
    const int j0   = blockIdx.x * 16;

    // tail-operand prefetch (consumed after the barrier)
    float xv0 = 0, xv1 = 0, xv2 = 0, xv3 = 0, cv = 0;
    const int tb = tid & 7;           // tail: batch
    const int tj = tid >> 3;          // tail: local col (valid tid<128)
    if (tid < 128) {
        size_t xb = ((size_t)tb*SEQ + t)*GD + j0 + tj;
        xv0 = xg[xb];
        xv1 = xg[xb + HID];
        xv2 = xg[xb + 2*HID];
        xv3 = xg[xb + 3*HID];
        cv  = (t > 0) ? c_state[(size_t)tb*HID + j0 + tj] : 0.0f;
    }

    if (t > 0) {
        const int kbase = kh*512 + l4*8;
        const unsigned short* wh = WhT_hi + (size_t)(gate*HID + j0 + l15)*HID + kbase;
        const unsigned short* wl = WhT_lo + (size_t)(gate*HID + j0 + l15)*HID + kbase;
        const unsigned short* ah = pp_rd_hi + (size_t)(l15 & 7)*HID + kbase;
        const unsigned short* al = pp_rd_lo + (size_t)(l15 & 7)*HID + kbase;

        f32x4 acc0 = {}, acc1 = {};    // 2 streams break the MFMA dep chain
        #pragma unroll
        for (int ks = 0; ks < 16; ks += 2) {
            short8 Ah0 = *(const short8*)(ah + ks*32);
            short8 Al0 = *(const short8*)(al + ks*32);
            short8 Bh0 = *(const short8*)(wh + ks*32);
            short8 Bl0 = *(const short8*)(wl + ks*32);
            short8 Ah1 = *(const short8*)(ah + (ks+1)*32);
            short8 Al1 = *(const short8*)(al + (ks+1)*32);
            short8 Bh1 = *(const short8*)(wh + (ks+1)*32);
            short8 Bl1 = *(const short8*)(wl + (ks+1)*32);
            acc0 = __builtin_amdgcn_mfma_f32_16x16x32_bf16(Ah0, Bh0, acc0, 0, 0, 0);
            acc1 = __builtin_amdgcn_mfma_f32_16x16x32_bf16(Ah1, Bh1, acc1, 0, 0, 0);
            acc0 = __builtin_amdgcn_mfma_f32_16x16x32_bf16(Ah0, Bl0, acc0, 0, 0, 0);
            acc1 = __builtin_amdgcn_mfma_f32_16x16x32_bf16(Ah1, Bl1, acc1, 0, 0, 0);
            acc0 = __builtin_amdgcn_mfma_f32_16x16x32_bf16(Al0, Bh0, acc0, 0, 0, 0);
            acc1 = __builtin_amdgcn_mfma_f32_16x16x32_bf16(Al1, Bh1, acc1, 0, 0, 0);
        }
        f32x4 acc = acc0 + acc1;
        // C/D: col = l15 (local gate-col), row = l4*4 + r (batch; 8-15 pad)
        *(f32x4*)&g_sm[kh][gate][l15][l4*4] = acc;
    }
    __syncthreads();

    if (tid < 128) {
        float s0 = 0, s1 = 0, s2 = 0, s3 = 0;
        if (t > 0) {
            s0 = g_sm[0][0][tj][tb] + g_sm[1][0][tj][tb];
            s1 = g_sm[0][1][tj][tb] + g_sm[1][1][tj][tb];
            s2 = g_sm[0][2][tj][tb] + g_sm[1][2][tj][tb];
            s3 = g_sm[0][3][tj][tb] + g_sm[1][3][tj][tb];
        }
        float iv = s0 + xv0;
        float fv = s1 + xv1;
        float gv = s2 + xv2;
        float ov = s3 + xv3;
        iv = 1.0f / (1.0f + expf(-iv));
        fv = 1.0f / (1.0f + expf(-fv));
        gv = tanhf(gv);
        ov = 1.0f / (1.0f + expf(-ov));
        float cn = fv*cv + iv*gv;
        float hn = ov * tanhf(cn);
        int jc = j0 + tj;
        c_state[(size_t)tb*HID + jc] = cn;
        size_t row = (size_t)tb*SEQ + t;
        hs_f32[row*HID + jc] = hn;
        unsigned hb = __float_as_uint(hn) & 0xFFFF0000u;
        unsigned short hu = (unsigned short)(hb >> 16);
        unsigned short lu =
            (unsigned short)(__float_as_uint(hn - __uint_as_float(hb)) >> 16);
        hs_hi[row*HID + jc] = hu;
        hs_lo[row*HID + jc] = lu;
        pp_wr_hi[(size_t)tb*HID + jc] = hu;
        pp_wr_lo[(size_t)tb*HID + jc] = lu;
    }
}

// ---------------------------------------------------------------------------
// Launch
// ---------------------------------------------------------------------------
extern "C" void kernel_launch(void* const* d_in, const int* in_sizes, int n_in,
                              void* d_out, int out_size, void* d_ws, size_t ws_size,
                              hipStream_t stream)
{
    const int*   ids    = (const int*)  d_in[0];
    const float* w_out  = (const float*)d_in[1];
    const float* b_out  = (const float*)d_in[2];
    const float* W_ih   = (const float*)d_in[3];
    const float* W_hh   = (const float*)d_in[4];
    const float* b_lstm = (const float*)d_in[5];
    float* out = (float*)d_out;

    // d_out scratch (524 MB): every region dead before the final GEMM writes C.
    char* ob = (char*)d_out;
    unsigned short* emb_hi  = (unsigned short*)(ob);               //  8,388,608 B
    unsigned short* emb_lo  = (unsigned short*)(ob + 8388608);     //  8,388,608 B
    unsigned short* whh_hiT = (unsigned short*)(ob + 16777216);    //  8,388,608 B
    unsigned short* whh_loT = (unsigned short*)(ob + 25165824);    //  8,388,608 B
    float*          xg      = (float*)(ob + 33554432);             // 67,108,864 B
    float*          cstate  = (float*)(ob + 100663296);            //     32,768 B
    unsigned short* pp0_hi  = (unsigned short*)(ob + 100696064);   //     16,384 B
    unsigned short* pp0_lo  = (unsigned short*)(ob + 100712448);   //     16,384 B
    unsigned short* pp1_hi  = (unsigned short*)(ob + 100728832);   //     16,384 B
    unsigned short* pp1_lo  = (unsigned short*)(ob + 100745216);   //     16,384 B
    unsigned short* wih_hiT = (unsigned short*)(ob + 100761600);   //  8,388,608 B
    unsigned short* wih_loT = (unsigned short*)(ob + 109150208);   //  8,388,608 B
    float*          hs_dout = (float*)(ob + 117538816);            // 16,777,216 B
    unsigned short* dum_hi  = (unsigned short*)(ob + 134316032);   //  8,388,608 B
    unsigned short* dum_lo  = (unsigned short*)(ob + 142704640);   //  8,388,608 B

    // d_ws: fast path needs hs_hi/lo + w_out^T hi/lo = 147,849,216 B.
    char* wb = (char*)d_ws;
    const size_t NEED = 147849216ull;
    const bool big_ws = (ws_size >= NEED);
    unsigned short* hs_hi  = (unsigned short*)(wb);                //  8,388,608 B
    unsigned short* hs_lo  = (unsigned short*)(wb + 8388608);      //  8,388,608 B
    unsigned short* wo_hiT = (unsigned short*)(wb + 16777216);     // 65,536,000 B
    unsigned short* wo_loT = (unsigned short*)(wb + 82313216);     // 65,536,000 B
    // fast path: hs f32 unused later -> d_out; fallback: hs f32 is GEMM2's A.
    float* hs_f32 = big_ws ? hs_dout : (float*)wb;
    // fast path: hs hi/lo are GEMM2's A (ws); fallback: dead stores into d_out.
    unsigned short* hsh = big_ws ? hs_hi : dum_hi;
    unsigned short* hsl = big_ws ? hs_lo : dum_lo;

    // 1) embedding gather (split to hi/lo bf16)
    k_gather_split<<<ROWS, 256, 0, stream>>>(ids, w_out, emb_hi, emb_lo);

    // 2) W_hh -> transposed hi/lo bf16 [4096][1024] (scan B-operand)
    k_transsplit<<<dim3(GD/32, HID/32), dim3(32, 8), 0, stream>>>(
        W_hh, whh_hiT, whh_loT, GD);

    // 2b) W_ih -> transposed hi/lo bf16 [4096][1024]
    k_transsplit<<<dim3(GD/32, HID/32), dim3(32, 8), 0, stream>>>(
        W_ih, wih_hiT, wih_loT, GD);

    // 3) x_gates = emb @ W_ih + b_lstm  (K-major fast MFMA GEMM)
    k_gemm_fast<<<dim3(GD/GBN, ROWS/GBM), 256, 0, stream>>>(
        emb_hi, emb_lo, wih_hiT, wih_loT, b_lstm, xg, ROWS, GD, HID);

    // 4) sequential scan: 512 lean launches (HW launch boundary = grid barrier)
    for (int t = 0; t < SEQ; ++t) {
        unsigned short* rd_hi = (t & 1) ? pp0_hi : pp1_hi;
        unsigned short* rd_lo = (t & 1) ? pp0_lo : pp1_lo;
        unsigned short* wr_hi = (t & 1) ? pp1_hi : pp0_hi;
        unsigned short* wr_lo = (t & 1) ? pp1_lo : pp0_lo;
        k_lstm_step3<<<64, 512, 0, stream>>>(
            xg, whh_hiT, whh_loT, rd_hi, rd_lo, wr_hi, wr_lo,
            cstate, hs_f32, hsh, hsl, t);
    }

    // 5) logits = hs @ w_out + b_out
    if (big_ws) {
        k_transsplit<<<dim3(VOCAB/32, HID/32), dim3(32, 8), 0, stream>>>(
            w_out, wo_hiT, wo_loT, VOCAB);
        k_gemm_fast<<<dim3(VOCAB/GBN, ROWS/GBM), 256, 0, stream>>>(
            hs_hi, hs_lo, wo_hiT, wo_loT, b_out, out, ROWS, VOCAB, HID);
    } else {
        k_gemm_mfma<<<dim3(VOCAB/GBN, ROWS/GBM), 256, 0, stream>>>(
            hs_f32, w_out, b_out, out, ROWS, VOCAB, HID);
    }
}